// Round 5
// baseline (111.558 us; speedup 1.0000x reference)
//
#include <hip/hip_runtime.h>
#include <math.h>

// DAS beamforming: out[b][c][p] = sum_s data[b][c][s][t(s,p)]
// Table chain: ONLY the f64-emulated chain is proven bit-exact (r5/r6/r8
// absmax 0.0). r7's native-f32 version regressed (3.56). DO NOT change it.
// r10: 8ch bf16 in one 16B slot, VMEM gather: total 96.5, gather ~40.
// r11/r12: LDS window staging: 49.5/60.4 -- occupancy+barrier serialization.
// r13: hybrid (tab patches in LDS, d2b direct): <44 but total 101 -- VMEM
//   count reduction bought ~0. CONCLUSION: gather is VALU-bound: ~26 VALU
//   wave-instrs/sensor (16 unpack/acc + ~10 addr) x 2cy x 128 x 16 waves/CU
//   = ~100k cy = 42us -- the invariant 40us.
// r14: compile error (helper declared after use). r15 = r14 fixed:
//   - v_sad_u32: patch byte addr = sad(sx,ix,0), sad(2sy,2iy,C), mad(,48,)
//     with C = -ax0*48-ay0*2 folded (mod 2^32 exact). 3 VALU.
//   - tab stores t<<4 (max 29824 fits u16): ds_read result IS the d2b byte
//     offset; d2b base per sensor is wave-uniform -> 0 VALU addressing.
//   - f32x2 ext-vector accumulators -> v_pk_add_f32: 4 pk-adds not 8 adds.
//     IEEE-identical values, same s-order -> absmax stays 0.25.
//   - prep kept at proven 1-px/thread 1024-block form.

#define NXY 512
#define S_CNT 128
#define T_CNT 2048
#define CH 8                       // B*2 = 4*2
#define CH_STRIDE (S_CNT * T_CNT)  // 262144 floats between channels (orig layout)
#define NPIX (NXY * NXY)
#define TAB_BYTES (NPIX * 2)       // 512 KB u16 table
#define CHUNK 32                   // sensors per LDS patch pass
#define NCHUNK (S_CNT / CHUNK)
#define PATW 24                    // staged table patch width (u16), 16B-aligned rows
#define PAT_ROW_B (PATW * 2)       // 48 bytes per patch row
#define PAT_SENS_B (16 * PAT_ROW_B)  // 768 bytes per sensor patch

typedef float f32x2 __attribute__((ext_vector_type(2)));

#if __has_builtin(__builtin_amdgcn_sad_u32)
__device__ __forceinline__ unsigned int sadu(unsigned int a, unsigned int b, unsigned int c) {
    return __builtin_amdgcn_sad_u32(a, b, c);
}
#else
__device__ __forceinline__ unsigned int sadu(unsigned int a, unsigned int b, unsigned int c) {
    return (a > b ? a - b : b - a) + c;  // compiler selects v_sad_u32
}
#endif

#pragma float_control(push)
#pragma float_control(precise, on)
__device__ __forceinline__ unsigned short delay_entry(int adx, int ady) {
    const double DX32 = (double)1e-4f;                        // f32 const, exact widen
    const double R1 = (double)(float)(1.0 / 1550.0);          // CR f32 reciprocal
    const double R2 = (double)(float)(1.0 / (double)2.5e-8f); // = 4.0e7 exactly
    float dxf = (float)((double)adx * DX32);        // exact f64 product -> f32 round
    float dyf = (float)((double)ady * DX32);
    float a2 = (float)((double)dxf * (double)dxf);  // exact in f64 -> f32 round
    float b2 = (float)((double)dyf * (double)dyf);  // exact in f64 -> f32 round
    float sum = (float)((double)a2 + (double)b2);   // exact in f64 -> f32 round
    float dis = (float)sqrt((double)sum);           // CR f32 sqrt
    float q1 = (float)((double)dis * R1);           // CR f32 mul
    float q2 = (float)((double)q1 * R2);            // CR f32 mul
    return (unsigned short)(int)q2;                 // trunc; max 1864
}

__device__ __forceinline__ unsigned int bf16_rne(float f) {
    unsigned int x = __float_as_uint(f);
    return (x + 0x7fffu + ((x >> 16) & 1u)) >> 16;  // round-to-nearest-even
}

// Fused (r10-proven shape, 1 px/thread, 1024 blocks): table (PRE-SCALED t<<4)
// + transpose-convert (8ch,128s,2048t)f32 -> (128s,2048t)x(8ch bf16 in 16B).
__global__ __launch_bounds__(256) void prep(const float* __restrict__ data,
                                            unsigned short* __restrict__ tab,
                                            uint4* __restrict__ d2b) {
    int idx = blockIdx.x * 256 + threadIdx.x;  // 0 .. 262143 (NPIX == 128*2048)
    tab[idx] = (unsigned short)((unsigned int)delay_entry(idx >> 9, idx & 511) << 4);

    unsigned int w[4];
#pragma unroll
    for (int j = 0; j < 4; ++j) {
        unsigned int lo = bf16_rne(data[(2 * j) * CH_STRIDE + idx]);
        unsigned int hi = bf16_rne(data[(2 * j + 1) * CH_STRIDE + idx]);
        w[j] = lo | (hi << 16);
    }
    d2b[idx] = make_uint4(w[0], w[1], w[2], w[3]);
}
#pragma float_control(pop)

__device__ __forceinline__ float bflo(unsigned int u) { return __uint_as_float(u << 16); }
__device__ __forceinline__ float bfhi(unsigned int u) { return __uint_as_float(u & 0xffff0000u); }

// Gather v5: tab patches in LDS (prescaled t<<4), sad addressing, pk_add acc.
// Wave = 8x8 px tile, block = 16x16 px (4 waves). 26.5 KB LDS.
__global__ __launch_bounds__(256) void das_sad(const uint4* __restrict__ d2b,
                                               const unsigned short* __restrict__ tab,
                                               const int* __restrict__ sxy,
                                               float* __restrict__ out) {
    __shared__ uint4 minfo[S_CNT];          // sx, 2*sy, C = -(ax0*48+ay0*2), 0
    __shared__ unsigned int mstage[S_CNT];  // ax0 | ay0<<16
    __shared__ uint4 patb[CHUNK * 16 * 3];  // raw (prescaled) tab patches, 24 KB

    int tid = threadIdx.x;
    int x0 = (blockIdx.x >> 5) << 4;  // tile origin
    int y0 = (blockIdx.x & 31) << 4;

    if (tid < S_CNT) {
        int sxv = sxy[2 * tid];
        int syv = sxy[2 * tid + 1];
        // component-wise min of |sx-ix|, |sy-iy| over the 16x16 tile
        int axm = sxv < x0 ? x0 - sxv : (sxv > x0 + 15 ? sxv - x0 - 15 : 0);
        int aym = syv < y0 ? y0 - syv : (syv > y0 + 15 ? syv - y0 - 15 : 0);
        int ay0 = aym & ~7;  // 16B-align patch row start
        minfo[tid] = make_uint4((unsigned int)sxv, (unsigned int)(2 * syv),
                                (unsigned int)(-(axm * 48 + ay0 * 2)), 0u);
        mstage[tid] = (unsigned int)(axm | (ay0 << 16));
    }
    __syncthreads();

    // lane bits: iy[2:0]=tid[2:0], ix[2:0]=tid[5:3]; wave bits: iy[3]=tid[6], ix[3]=tid[7]
    int iy = y0 | (((tid >> 6) & 1) << 3) | (tid & 7);
    int ix = x0 | ((tid >> 7) << 3) | ((tid >> 3) & 7);
    unsigned int uix = (unsigned int)ix;
    unsigned int uiy2 = (unsigned int)(2 * iy);

    f32x2 acc2[4];
#pragma unroll
    for (int k = 0; k < 4; ++k) acc2[k] = (f32x2){0.0f, 0.0f};

    const char* patc = (const char*)patb;

    for (int c = 0; c < NCHUNK; ++c) {
        int s0 = c * CHUNK;

        // --- stage raw tab patches: 32 sensors x 16 rows x 3 uint4 = 24 KB,
        // 6 coalesced dwordx4 per thread. Rows 16B-aligned (ay0 even-8).
        // Worst case reads 16B past table end (into d2b base) - staged, unused.
#pragma unroll
        for (int j = 0; j < 6; ++j) {
            unsigned int idx = (unsigned int)tid + 256u * j;  // 0..1535
            unsigned int r3 = idx / 3u;                       // magic mul
            unsigned int cc = idx - r3 * 3u;
            unsigned int row = r3 & 15u;
            unsigned int ls = r3 >> 4;
            unsigned int st = mstage[s0 + ls];
            int ax0 = (int)(st & 0xffffu);
            int ay0 = (int)(st >> 16);
            const uint4* src = (const uint4*)((const char*)tab +
                (((size_t)(ax0 + (int)row) << 10) + ((size_t)ay0 << 1) + ((size_t)cc << 4)));
            patb[ls * 48u + row * 3u + cc] = *src;
        }
        __syncthreads();

        // --- inner: 3 VALU addr (sad,sad,mad) + ds_read_u16 + uniform-base
        // VMEM b128 + 8 unpack + 4 pk_add per sensor.
        const char* d2bc = (const char*)d2b + ((size_t)s0 << 15);
#pragma unroll 8
        for (int ls = 0; ls < CHUNK; ++ls) {
            uint4 mi = minfo[s0 + ls];  // b128 broadcast (conflict-free)
            unsigned int b1 = sadu(mi.x, uix, 0u);        // |sx-ix|
            unsigned int b2 = sadu(mi.y, uiy2, mi.z);     // 2|sy-iy| + C (mod 2^32)
            unsigned int byte = b1 * 48u + b2;            // mad, 48 inline const
            unsigned int t16 = (unsigned int)*(const unsigned short*)(
                patc + (size_t)(ls * PAT_SENS_B) + byte); // prescaled t<<4
            uint4 w = *(const uint4*)(d2bc + ((size_t)ls << 15) + t16);
            f32x2 p0 = {bflo(w.x), bfhi(w.x)};  // ch0,1
            f32x2 p1 = {bflo(w.y), bfhi(w.y)};  // ch2,3
            f32x2 p2 = {bflo(w.z), bfhi(w.z)};  // ch4,5
            f32x2 p3 = {bflo(w.w), bfhi(w.w)};  // ch6,7
            acc2[0] += p0;  // v_pk_add_f32; per-channel s-ascending order kept
            acc2[1] += p1;
            acc2[2] += p2;
            acc2[3] += p3;
        }
        __syncthreads();  // protect patb before next chunk's staging
    }

    int pix = (ix << 9) | iy;
#pragma unroll
    for (int k = 0; k < 4; ++k) {
        out[(2 * k) * NPIX + pix] = acc2[k].x;
        out[(2 * k + 1) * NPIX + pix] = acc2[k].y;
    }
}

// ---------- fallback path (ws too small): r5-proven build_table + das_main ----------
#pragma float_control(push)
#pragma float_control(precise, on)
__global__ __launch_bounds__(256) void build_table(unsigned short* __restrict__ tab) {
    int idx = blockIdx.x * 256 + threadIdx.x;
    tab[idx] = delay_entry(idx >> 9, idx & 511);  // RAW (unscaled) for das_main
}
#pragma float_control(pop)

__global__ __launch_bounds__(256) void das_main(const float* __restrict__ data,
                                                const unsigned short* __restrict__ tab,
                                                const int* __restrict__ sxy,
                                                float* __restrict__ out) {
    __shared__ int sx[S_CNT];
    __shared__ int sy[S_CNT];
    int tid = threadIdx.x;
    if (tid < S_CNT) {
        sx[tid] = sxy[2 * tid];
        sy[tid] = sxy[2 * tid + 1];
    }
    __syncthreads();
    int iy = ((blockIdx.x & 31) << 4) | (tid & 15);
    int ix = ((blockIdx.x >> 5) << 4) | (tid >> 4);
    float acc[CH];
#pragma unroll
    for (int k = 0; k < CH; ++k) acc[k] = 0.0f;
#pragma unroll 4
    for (int s = 0; s < S_CNT; ++s) {
        int dxi = sx[s] - ix;
        int dyi = sy[s] - iy;
        int adx = dxi < 0 ? -dxi : dxi;
        int ady = dyi < 0 ? -dyi : dyi;
        int t = (int)tab[(adx << 9) | ady];
        const float* p = data + (s << 11) + t;
#pragma unroll
        for (int k = 0; k < CH; ++k) acc[k] += p[(size_t)k * CH_STRIDE];
    }
    int pix = (ix << 9) | iy;
#pragma unroll
    for (int k = 0; k < CH; ++k) out[k * NPIX + pix] = acc[k];
}

extern "C" void kernel_launch(void* const* d_in, const int* in_sizes, int n_in,
                              void* d_out, int out_size, void* d_ws, size_t ws_size,
                              hipStream_t stream) {
    const float* data = (const float*)d_in[0];     // (4,2,128,2048) f32
    const int* sxy = (const int*)d_in[1];          // (128,2) i32
    float* out = (float*)d_out;                    // (4,2,512,512) f32
    unsigned short* tab = (unsigned short*)d_ws;   // 512 KB

    size_t need = (size_t)TAB_BYTES + (size_t)CH_STRIDE * 16;  // 512KB + 4MB
    if (ws_size >= need) {
        uint4* d2b = (uint4*)((char*)d_ws + TAB_BYTES);
        prep<<<NPIX / 256, 256, 0, stream>>>(data, tab, d2b);
        das_sad<<<1024, 256, 0, stream>>>(d2b, tab, sxy, out);
    } else {
        build_table<<<NPIX / 256, 256, 0, stream>>>(tab);
        das_main<<<1024, 256, 0, stream>>>(data, tab, sxy, out);
    }
}

// Round 6
// 101.469 us; speedup vs baseline: 1.0994x; 1.0994x over previous
//
#include <hip/hip_runtime.h>
#include <math.h>

// DAS beamforming: out[b][c][p] = sum_s data[b][c][s][t(s,p)]
// Table chain: ONLY the f64-emulated chain is proven bit-exact (r5/r6/r8
// absmax 0.0). r7's native-f32 version regressed (3.56). DO NOT change it.
// r10: 8ch bf16 in one 16B slot, divergent VMEM gather: total 96.5, gather ~40.
// r11/r12: 32-sensor LDS window staging: 49.5/60.4 (2 blk/CU, serial chains).
// r13: tab patches in LDS + direct d2b: <44. r15: +sad/prescale/pk_add: 53.7
//   (VGPR 40 killed MLP). ACCOUNTING CLOSED: divergent d2b gather = ~47cyc/
//   wave-instr of TA pipe (lanes span ~10-15 lines) -> 40us floor for ANY
//   structure issuing 128 divergent wave-gathers. Must coalesce.
// r16 (this round): windows v2 with r11's failure modes fixed.
//   - CHUNK=8 -> 17KB LDS -> 8 blocks/CU (was 2).
//   - window staged by 2 coalesced dwordx4/thread/pass; TA pipe ~10x down.
//   - patch stores PRE-SUBTRACTED PRE-SWIZZLED (t-tmin)<<4: ds_read_u16
//     result IS the window byte offset (0 VALU between the LDS reads).
//   - window bank swizzle byte^=((e>>3)&3)<<4 folded into patch values.
//   - phase-split t-lookups / window-reads over the 8 sensors for ILP.
//   Same values, same s-ascending order -> absmax stays 0.25.

#define NXY 512
#define S_CNT 128
#define T_CNT 2048
#define CH 8                       // B*2 = 4*2
#define CH_STRIDE (S_CNT * T_CNT)  // 262144 floats between channels (orig layout)
#define NPIX (NXY * NXY)
#define TAB_BYTES (NPIX * 2)       // 512 KB u16 table (prescaled t<<4)
#define CHUNK 8                    // sensors per LDS pass
#define NCHUNK (S_CNT / CHUNK)     // 16 passes
#define WIN 64                     // window entries per sensor (span <= 56 proven)
#define PATW 24                    // patch width u16 (16B-aligned rows)
#define PAT_ROW_B (PATW * 2)       // 48 B/row
#define PAT_SENS_B (16 * PAT_ROW_B)  // 768 B/sensor

typedef float f32x2 __attribute__((ext_vector_type(2)));

#if __has_builtin(__builtin_amdgcn_sad_u32)
__device__ __forceinline__ unsigned int sadu(unsigned int a, unsigned int b, unsigned int c) {
    return __builtin_amdgcn_sad_u32(a, b, c);
}
#else
__device__ __forceinline__ unsigned int sadu(unsigned int a, unsigned int b, unsigned int c) {
    return (a > b ? a - b : b - a) + c;  // compiler selects v_sad_u32
}
#endif

__device__ __forceinline__ unsigned short delay_entry(int adx, int ady) {
    const double DX32 = (double)1e-4f;                        // f32 const, exact widen
    const double R1 = (double)(float)(1.0 / 1550.0);          // CR f32 reciprocal
    const double R2 = (double)(float)(1.0 / (double)2.5e-8f); // = 4.0e7 exactly
    float dxf = (float)((double)adx * DX32);        // exact f64 product -> f32 round
    float dyf = (float)((double)ady * DX32);
    float a2 = (float)((double)dxf * (double)dxf);  // exact in f64 -> f32 round
    float b2 = (float)((double)dyf * (double)dyf);  // exact in f64 -> f32 round
    float sum = (float)((double)a2 + (double)b2);   // exact in f64 -> f32 round
    float dis = (float)sqrt((double)sum);           // CR f32 sqrt
    float q1 = (float)((double)dis * R1);           // CR f32 mul
    float q2 = (float)((double)q1 * R2);            // CR f32 mul
    return (unsigned short)(int)q2;                 // trunc; max 1864
}

__device__ __forceinline__ unsigned int bf16_rne(float f) {
    unsigned int x = __float_as_uint(f);
    return (x + 0x7fffu + ((x >> 16) & 1u)) >> 16;  // round-to-nearest-even
}

// Fused (r10-proven shape): table PRE-SCALED t<<4 + transpose-convert
// (8ch,128s,2048t)f32 -> (128s,2048t)x(8ch bf16 in 16B).
__global__ __launch_bounds__(256) void prep(const float* __restrict__ data,
                                            unsigned short* __restrict__ tab,
                                            uint4* __restrict__ d2b) {
    int idx = blockIdx.x * 256 + threadIdx.x;  // 0 .. 262143 (NPIX == 128*2048)
    tab[idx] = (unsigned short)((unsigned int)delay_entry(idx >> 9, idx & 511) << 4);

    unsigned int w[4];
#pragma unroll
    for (int j = 0; j < 4; ++j) {
        unsigned int lo = bf16_rne(data[(2 * j) * CH_STRIDE + idx]);
        unsigned int hi = bf16_rne(data[(2 * j + 1) * CH_STRIDE + idx]);
        w[j] = lo | (hi << 16);
    }
    d2b[idx] = make_uint4(w[0], w[1], w[2], w[3]);
}

__device__ __forceinline__ float bflo(unsigned int u) { return __uint_as_float(u << 16); }
__device__ __forceinline__ float bfhi(unsigned int u) { return __uint_as_float(u & 0xffff0000u); }

// window bank swizzle: entry byte offset d (=e<<4): XOR bits[5:4] with e[4:3]
__device__ __forceinline__ unsigned int swz16(unsigned int d) {
    return d ^ (((d >> 7) & 3u) << 4);
}
// per-halfword: swz((a - tm4) mod 2^16); used entries land in [0, 56<<4]
__device__ __forceinline__ unsigned int subswz_x2(unsigned int a, unsigned int tm4) {
    unsigned int lo = swz16((a - tm4) & 0xffffu);
    unsigned int hi = swz16(((a >> 16) - tm4) & 0xffffu);
    return lo | (hi << 16);
}

// Gather v6: 8-sensor LDS windows (swizzled) + patches (pre-sub/pre-swz).
// Wave = 8x8 px tile, block = 16x16 px (4 waves). ~17 KB LDS -> 8 blocks/CU.
__global__ __launch_bounds__(256) void das_win(const uint4* __restrict__ d2b,
                                               const unsigned short* __restrict__ tab,
                                               const int* __restrict__ sxy,
                                               float* __restrict__ out) {
    __shared__ uint4 minfo[S_CNT];           // sx, 2*sy, C=-(ax0*48+ay0*2), 0
    __shared__ uint2 mstage[S_CNT];          // ax0|ay0<<16, tmin<<4
    __shared__ uint4 winb[CHUNK * WIN];      // swizzled d2b windows, 8 KB
    __shared__ uint4 patb[CHUNK * 16 * 3];   // (t-tmin)<<4 swizzled patches, 6 KB

    int tid = threadIdx.x;
    int x0 = (blockIdx.x >> 5) << 4;  // tile origin
    int y0 = (blockIdx.x & 31) << 4;

    if (tid < S_CNT) {
        int sxv = sxy[2 * tid];
        int syv = sxy[2 * tid + 1];
        // component-wise min of |sx-ix|, |sy-iy| over the 16x16 tile
        int axm = sxv < x0 ? x0 - sxv : (sxv > x0 + 15 ? sxv - x0 - 15 : 0);
        int aym = syv < y0 ? y0 - syv : (syv > y0 + 15 ? syv - y0 - 15 : 0);
        int ay0 = aym & ~7;                    // 16B-align patch row start
        int tmin = (int)delay_entry(axm, aym); // exact monotone lower bound
        minfo[tid] = make_uint4((unsigned int)sxv, (unsigned int)(2 * syv),
                                (unsigned int)(-(axm * 48 + ay0 * 2)), 0u);
        mstage[tid] = make_uint2((unsigned int)(axm | (ay0 << 16)),
                                 (unsigned int)(tmin << 4));
    }
    __syncthreads();

    // lane bits: iy[2:0]=tid[2:0], ix[2:0]=tid[5:3]; wave bits: iy[3]=tid[6], ix[3]=tid[7]
    int iy = y0 | (((tid >> 6) & 1) << 3) | (tid & 7);
    int ix = x0 | ((tid >> 7) << 3) | ((tid >> 3) & 7);
    unsigned int uix = (unsigned int)ix;
    unsigned int uiy2 = (unsigned int)(2 * iy);

    f32x2 acc2[4];
#pragma unroll
    for (int k = 0; k < 4; ++k) acc2[k] = (f32x2){0.0f, 0.0f};

    char* winc = (char*)winb;
    char* patc = (char*)patb;

    for (int c = 0; c < NCHUNK; ++c) {
        int s0 = c * CHUNK;

        // --- stage windows: 8 sensors x 64 x 16B = 8 KB, 2 coalesced
        // dwordx4/thread. Sensor ls=tid>>5, entries e0=tid&31 and e0+32
        // (same swizzle nibble for both). tmin+63 <= 1927 < 2048: in-row.
        {
            int lsw = tid >> 5;                 // 0..7
            int e0 = tid & 31;
            uint2 st = mstage[s0 + lsw];
            const uint4* src = d2b + ((size_t)(s0 + lsw) << 11) + (st.y >> 4) + e0;
            unsigned int sw = (((unsigned int)e0 >> 3) & 3u) << 4;
            unsigned int slot = ((unsigned int)lsw << 10) | (((unsigned int)e0 << 4) ^ sw);
            uint4 v0 = src[0];
            uint4 v1 = src[32];
            *(uint4*)(winc + slot) = v0;
            *(uint4*)(winc + slot + 512u) = v1;   // entry e0+32, same sw
        }

        // --- stage patches: 8 sensors x 16 rows x 3 uint4 = 384 loads;
        // pre-subtract tmin<<4 and pre-swizzle per halfword.
        // Worst case reads past table end (into d2b) - staged, never read.
#pragma unroll
        for (int j = 0; j < 2; ++j) {
            unsigned int idx = (unsigned int)tid + 256u * j;  // 0..511
            if (idx < 384u) {
                unsigned int r3 = idx / 3u;                   // magic mul
                unsigned int cc = idx - r3 * 3u;
                unsigned int row = r3 & 15u;
                unsigned int ls = r3 >> 4;                    // 0..7
                uint2 st = mstage[s0 + ls];
                int ax0 = (int)(st.x & 0xffffu);
                int ay0 = (int)(st.x >> 16);
                unsigned int tm4 = st.y;
                uint4 v = *(const uint4*)((const char*)tab +
                    (((size_t)(ax0 + (int)row) << 10) + ((size_t)ay0 << 1) + ((size_t)cc << 4)));
                v.x = subswz_x2(v.x, tm4);
                v.y = subswz_x2(v.y, tm4);
                v.z = subswz_x2(v.z, tm4);
                v.w = subswz_x2(v.w, tm4);
                patb[ls * 48u + row * 3u + cc] = v;
            }
        }
        __syncthreads();

        // --- phase A: 8 independent t-lookups (sad,sad,mad + ds_read_u16)
        unsigned int t16[CHUNK];
#pragma unroll
        for (int j = 0; j < CHUNK; ++j) {
            uint4 mi = minfo[s0 + j];                 // b128 broadcast
            unsigned int b1 = sadu(mi.x, uix, 0u);    // |sx-ix|
            unsigned int b2 = sadu(mi.y, uiy2, mi.z); // 2|sy-iy| + C (mod 2^32)
            unsigned int byte = b1 * 48u + b2;        // patch byte offset
            t16[j] = (unsigned int)*(const unsigned short*)(
                patc + (unsigned int)(j * PAT_SENS_B) + byte);  // swz((t-tmin)<<4)
        }

        // --- phase B: 8 independent swizzled window b128 reads + accumulate
#pragma unroll
        for (int j = 0; j < CHUNK; ++j) {
            uint4 w = *(const uint4*)(winc + (unsigned int)(j << 10) + t16[j]);
            f32x2 p0 = {bflo(w.x), bfhi(w.x)};  // ch0,1
            f32x2 p1 = {bflo(w.y), bfhi(w.y)};  // ch2,3
            f32x2 p2 = {bflo(w.z), bfhi(w.z)};  // ch4,5
            f32x2 p3 = {bflo(w.w), bfhi(w.w)};  // ch6,7
            acc2[0] += p0;  // v_pk_add_f32; per-channel s-ascending order kept
            acc2[1] += p1;
            acc2[2] += p2;
            acc2[3] += p3;
        }
        __syncthreads();  // protect winb/patb before next pass
    }

    int pix = (ix << 9) | iy;
#pragma unroll
    for (int k = 0; k < 4; ++k) {
        out[(2 * k) * NPIX + pix] = acc2[k].x;
        out[(2 * k + 1) * NPIX + pix] = acc2[k].y;
    }
}

// ---------- fallback path (ws too small): r5-proven build_table + das_main ----------
__global__ __launch_bounds__(256) void build_table(unsigned short* __restrict__ tab) {
    int idx = blockIdx.x * 256 + threadIdx.x;
    tab[idx] = delay_entry(idx >> 9, idx & 511);  // RAW (unscaled) for das_main
}

__global__ __launch_bounds__(256) void das_main(const float* __restrict__ data,
                                                const unsigned short* __restrict__ tab,
                                                const int* __restrict__ sxy,
                                                float* __restrict__ out) {
    __shared__ int sx[S_CNT];
    __shared__ int sy[S_CNT];
    int tid = threadIdx.x;
    if (tid < S_CNT) {
        sx[tid] = sxy[2 * tid];
        sy[tid] = sxy[2 * tid + 1];
    }
    __syncthreads();
    int iy = ((blockIdx.x & 31) << 4) | (tid & 15);
    int ix = ((blockIdx.x >> 5) << 4) | (tid >> 4);
    float acc[CH];
#pragma unroll
    for (int k = 0; k < CH; ++k) acc[k] = 0.0f;
#pragma unroll 4
    for (int s = 0; s < S_CNT; ++s) {
        int dxi = sx[s] - ix;
        int dyi = sy[s] - iy;
        int adx = dxi < 0 ? -dxi : dxi;
        int ady = dyi < 0 ? -dyi : dyi;
        int t = (int)tab[(adx << 9) | ady];
        const float* p = data + (s << 11) + t;
#pragma unroll
        for (int k = 0; k < CH; ++k) acc[k] += p[(size_t)k * CH_STRIDE];
    }
    int pix = (ix << 9) | iy;
#pragma unroll
    for (int k = 0; k < CH; ++k) out[k * NPIX + pix] = acc[k];
}

extern "C" void kernel_launch(void* const* d_in, const int* in_sizes, int n_in,
                              void* d_out, int out_size, void* d_ws, size_t ws_size,
                              hipStream_t stream) {
    const float* data = (const float*)d_in[0];     // (4,2,128,2048) f32
    const int* sxy = (const int*)d_in[1];          // (128,2) i32
    float* out = (float*)d_out;                    // (4,2,512,512) f32
    unsigned short* tab = (unsigned short*)d_ws;   // 512 KB

    size_t need = (size_t)TAB_BYTES + (size_t)CH_STRIDE * 16;  // 512KB + 4MB
    if (ws_size >= need) {
        uint4* d2b = (uint4*)((char*)d_ws + TAB_BYTES);
        prep<<<NPIX / 256, 256, 0, stream>>>(data, tab, d2b);
        das_win<<<1024, 256, 0, stream>>>(d2b, tab, sxy, out);
    } else {
        build_table<<<NPIX / 256, 256, 0, stream>>>(tab);
        das_main<<<1024, 256, 0, stream>>>(data, tab, sxy, out);
    }
}

// Round 9
// 100.750 us; speedup vs baseline: 1.1073x; 1.0071x over previous
//
#include <hip/hip_runtime.h>
#include <math.h>

// DAS beamforming: out[b][c][p] = sum_s data[b][c][s][t(s,p)]
// Table chain: ONLY the f64-emulated chain is proven bit-exact (r5/r6/r8
// absmax 0.0). r7's native-f32 version regressed (3.56). DO NOT change it.
// r10: divergent VMEM gather ~40us. r11-r15: every restructure lands 40-54us.
// r16: 8-sensor LDS windows, 2 barriers/pass: 45.5us. Accounting: inner loop
//   = 3 LDS reads/pair (minfo b128 bcast + patch u16 + window b128) ~26us of
//   LDS pipe + 32 barriers with exposed VMEM stage latency.
// r17/r18: SGPR meta + double-buffer. Bench infra failed both times PRE-
//   EXECUTION (no timing dict -- container never acquired; cf. r4's compile
//   fail which still had pytest output). Kernel audited twice: window VMEM
//   max idx 262023<262144, patch overrun lands in d2b (same ws), LDS t16
//   <= 944 < 1024, uniform barriers. r19 = identical third submit.
//   - per-(tile,sensor) meta {sx,2sy,ax0|ay0<<16,tmin<<4} precomputed into
//     GLOBAL (in prep; 2MB) and read in the inner loop via blockIdx-uniform
//     address -> s_load_dwordx4 (SGPR). Deletes the b128 minfo broadcast
//     (~10us LDS) + decode moves to SALU. Inner = 2 LDS/pair (the floor).
//   - double-buffered windows/patches: issue pass c+1 loads -> INNER(c) ->
//     ds_write -> ONE barrier. 17 barriers total, VMEM hidden under compute.
//   Same values, same s-ascending order -> absmax stays 0.25.

#define NXY 512
#define S_CNT 128
#define T_CNT 2048
#define CH 8                       // B*2 = 4*2
#define CH_STRIDE (S_CNT * T_CNT)  // 262144 floats between channels (orig layout)
#define NPIX (NXY * NXY)
#define NTILE 1024                 // 32x32 tiles of 16x16 px
#define TAB_BYTES (NPIX * 2)       // 512 KB u16 table (prescaled t<<4)
#define D2B_BYTES (CH_STRIDE * 16) // 4 MB
#define META_BYTES (NTILE * S_CNT * 16)  // 2 MB
#define CHUNK 8                    // sensors per LDS pass
#define NCHUNK (S_CNT / CHUNK)     // 16 passes
#define WIN 64                     // window entries per sensor (span <= 56 proven)
#define PATW 24                    // patch width u16 (16B-aligned rows)
#define PAT_SENS_B (16 * PATW * 2) // 768 B/sensor

typedef float f32x2 __attribute__((ext_vector_type(2)));

#if __has_builtin(__builtin_amdgcn_sad_u32)
__device__ __forceinline__ unsigned int sadu(unsigned int a, unsigned int b, unsigned int c) {
    return __builtin_amdgcn_sad_u32(a, b, c);
}
#else
__device__ __forceinline__ unsigned int sadu(unsigned int a, unsigned int b, unsigned int c) {
    return (a > b ? a - b : b - a) + c;  // compiler selects v_sad_u32
}
#endif

__device__ __forceinline__ unsigned short delay_entry(int adx, int ady) {
    const double DX32 = (double)1e-4f;                        // f32 const, exact widen
    const double R1 = (double)(float)(1.0 / 1550.0);          // CR f32 reciprocal
    const double R2 = (double)(float)(1.0 / (double)2.5e-8f); // = 4.0e7 exactly
    float dxf = (float)((double)adx * DX32);        // exact f64 product -> f32 round
    float dyf = (float)((double)ady * DX32);
    float a2 = (float)((double)dxf * (double)dxf);  // exact in f64 -> f32 round
    float b2 = (float)((double)dyf * (double)dyf);  // exact in f64 -> f32 round
    float sum = (float)((double)a2 + (double)b2);   // exact in f64 -> f32 round
    float dis = (float)sqrt((double)sum);           // CR f32 sqrt
    float q1 = (float)((double)dis * R1);           // CR f32 mul
    float q2 = (float)((double)q1 * R2);            // CR f32 mul
    return (unsigned short)(int)q2;                 // trunc; max 1864
}

__device__ __forceinline__ unsigned int bf16_rne(float f) {
    unsigned int x = __float_as_uint(f);
    return (x + 0x7fffu + ((x >> 16) & 1u)) >> 16;  // round-to-nearest-even
}

// Fused: prescaled table + bf16 transpose-pack + per-(tile,sensor) META.
__global__ __launch_bounds__(256) void prep(const float* __restrict__ data,
                                            const int* __restrict__ sxy,
                                            unsigned short* __restrict__ tab,
                                            uint4* __restrict__ d2b,
                                            uint4* __restrict__ meta) {
    int idx = blockIdx.x * 256 + threadIdx.x;  // 0 .. 262143 (NPIX == 128*2048)
    tab[idx] = (unsigned short)((unsigned int)delay_entry(idx >> 9, idx & 511) << 4);

    unsigned int w[4];
#pragma unroll
    for (int j = 0; j < 4; ++j) {
        unsigned int lo = bf16_rne(data[(2 * j) * CH_STRIDE + idx]);
        unsigned int hi = bf16_rne(data[(2 * j + 1) * CH_STRIDE + idx]);
        w[j] = lo | (hi << 16);
    }
    d2b[idx] = make_uint4(w[0], w[1], w[2], w[3]);

    if (idx < NTILE * S_CNT) {
        int tile = idx >> 7;
        int s = idx & 127;
        int x0 = (tile >> 5) << 4;
        int y0 = (tile & 31) << 4;
        int sxv = sxy[2 * s];
        int syv = sxy[2 * s + 1];
        int axm = sxv < x0 ? x0 - sxv : (sxv > x0 + 15 ? sxv - x0 - 15 : 0);
        int aym = syv < y0 ? y0 - syv : (syv > y0 + 15 ? syv - y0 - 15 : 0);
        int ay0 = aym & ~7;                          // 16B-align patch rows
        int tmin = (int)delay_entry(axm, aym);       // exact monotone lower bound
        meta[idx] = make_uint4((unsigned int)sxv, (unsigned int)(2 * syv),
                               (unsigned int)(axm | (ay0 << 16)),
                               (unsigned int)(tmin << 4));
    }
}

__device__ __forceinline__ float bflo(unsigned int u) { return __uint_as_float(u << 16); }
__device__ __forceinline__ float bfhi(unsigned int u) { return __uint_as_float(u & 0xffff0000u); }

// window bank swizzle: entry byte offset d (=e<<4): XOR bits[5:4] with e[4:3]
__device__ __forceinline__ unsigned int swz16(unsigned int d) {
    return d ^ (((d >> 7) & 3u) << 4);
}
// per-halfword: swz((a - tm4) mod 2^16); used entries land in [0, 56<<4]
__device__ __forceinline__ unsigned int subswz_x2(unsigned int a, unsigned int tm4) {
    unsigned int lo = swz16((a - tm4) & 0xffffu);
    unsigned int hi = swz16(((a >> 16) - tm4) & 0xffffu);
    return lo | (hi << 16);
}

// Gather v7: SGPR meta + double-buffered 8-sensor windows, 1 barrier/pass.
// Wave = 8x8 px tile, block = 16x16 px (4 waves). ~30 KB LDS.
__global__ __launch_bounds__(256) void das_smeta(const uint4* __restrict__ d2b,
                                                 const uint4* __restrict__ meta,
                                                 float* __restrict__ out) {
    __shared__ uint2 mstage[S_CNT];            // ax0|ay0<<16, tmin<<4 (1 KB)
    __shared__ uint4 winb[2][CHUNK * WIN];     // swizzled windows, 2 x 8 KB
    __shared__ uint4 patb[2][CHUNK * 16 * 3];  // pre-sub/pre-swz patches, 2 x 6 KB

    int tid = threadIdx.x;
    const uint4* mblk = meta + ((size_t)blockIdx.x << 7);  // uniform base

    if (tid < S_CNT) {
        uint4 m = mblk[tid];
        mstage[tid] = make_uint2(m.z, m.w);
    }
    __syncthreads();

    // lane bits: iy[2:0]=tid[2:0], ix[2:0]=tid[5:3]; wave bits: iy[3]=tid[6], ix[3]=tid[7]
    int y0 = (blockIdx.x & 31) << 4;
    int x0 = (blockIdx.x >> 5) << 4;
    int iy = y0 | (((tid >> 6) & 1) << 3) | (tid & 7);
    int ix = x0 | ((tid >> 7) << 3) | ((tid >> 3) & 7);
    unsigned int uix = (unsigned int)ix;
    unsigned int uiy2 = (unsigned int)(2 * iy);

    f32x2 acc2[4];
#pragma unroll
    for (int k = 0; k < 4; ++k) acc2[k] = (f32x2){0.0f, 0.0f};

    // prefetch registers (pass c+1 in flight during INNER(c))
    uint4 rw0, rw1;            // window entries e0, e0+32
    uint4 rp0, rp1;            // raw patch quads
    unsigned int wslot, pslot0, pslot1, ptm0, ptm1;
    const int lsw = tid >> 5, e0 = tid & 31;
    const unsigned int swn = (((unsigned int)e0 >> 3) & 3u) << 4;
    const bool p1act = tid < 128;  // patch idx tid+256 in [256,384)

#define ISSUE(cc)                                                                     \
    {                                                                                 \
        int s0n = (cc) * CHUNK;                                                       \
        uint2 stw = mstage[s0n + lsw];                                                \
        const uint4* wsrc = d2b + ((size_t)(s0n + lsw) << 11) + (stw.y >> 4) + e0;    \
        rw0 = wsrc[0];                                                                \
        rw1 = wsrc[32];                                                               \
        wslot = ((unsigned int)lsw << 10) | (((unsigned int)e0 << 4) ^ swn);          \
        {                                                                             \
            unsigned int pidx = (unsigned int)tid;                                    \
            unsigned int r3 = pidx / 3u, cc2 = pidx - r3 * 3u;                        \
            unsigned int row = r3 & 15u, ls = r3 >> 4;                                \
            uint2 stp = mstage[s0n + ls];                                             \
            rp0 = *(const uint4*)((const char*)tab_g +                                \
                ((((stp.x & 0xffffu) + row) << 10) + ((stp.x >> 16) << 1) + (cc2 << 4))); \
            pslot0 = ls * 768u + row * 48u + cc2 * 16u;                               \
            ptm0 = stp.y;                                                             \
        }                                                                             \
        if (p1act) {                                                                  \
            unsigned int pidx = (unsigned int)tid + 256u;                             \
            unsigned int r3 = pidx / 3u, cc2 = pidx - r3 * 3u;                        \
            unsigned int row = r3 & 15u, ls = r3 >> 4;                                \
            uint2 stp = mstage[s0n + ls];                                             \
            rp1 = *(const uint4*)((const char*)tab_g +                                \
                ((((stp.x & 0xffffu) + row) << 10) + ((stp.x >> 16) << 1) + (cc2 << 4))); \
            pslot1 = ls * 768u + row * 48u + cc2 * 16u;                               \
            ptm1 = stp.y;                                                             \
        }                                                                             \
    }

#define WRITEBUF(cc)                                                                  \
    {                                                                                 \
        char* wb = (char*)winb[(cc) & 1];                                             \
        char* pb = (char*)patb[(cc) & 1];                                             \
        *(uint4*)(wb + wslot) = rw0;                                                  \
        *(uint4*)(wb + wslot + 512u) = rw1;                                           \
        uint4 v = rp0;                                                                \
        v.x = subswz_x2(v.x, ptm0);                                                   \
        v.y = subswz_x2(v.y, ptm0);                                                   \
        v.z = subswz_x2(v.z, ptm0);                                                   \
        v.w = subswz_x2(v.w, ptm0);                                                   \
        *(uint4*)(pb + pslot0) = v;                                                   \
        if (p1act) {                                                                  \
            uint4 u = rp1;                                                            \
            u.x = subswz_x2(u.x, ptm1);                                               \
            u.y = subswz_x2(u.y, ptm1);                                               \
            u.z = subswz_x2(u.z, ptm1);                                               \
            u.w = subswz_x2(u.w, ptm1);                                               \
            *(uint4*)(pb + pslot1) = u;                                               \
        }                                                                             \
    }

    // tab lives immediately before d2b in ws: recover its base from d2b.
    const char* tab_g = (const char*)d2b - TAB_BYTES;

    ISSUE(0);
    WRITEBUF(0);
    __syncthreads();

    for (int c = 0; c < NCHUNK; ++c) {
        if (c + 1 < NCHUNK) ISSUE(c + 1);

        {  // INNER(c): SGPR meta, 2 LDS reads/pair, phase-split for ILP
            const char* patc = (const char*)patb[c & 1];
            const char* winc = (const char*)winb[c & 1];
            int s0 = c * CHUNK;
            unsigned int t16[CHUNK];
#pragma unroll
            for (int j = 0; j < CHUNK; ++j) {
                uint4 m = mblk[s0 + j];  // uniform -> s_load_dwordx4
                unsigned int Cc = 0u - ((m.z & 0xffffu) * 48u + (m.z >> 16) * 2u);  // SALU
                unsigned int b1 = sadu(m.x, uix, 0u);      // |sx-ix|
                unsigned int b2 = sadu(m.y, uiy2, 0u);     // 2|sy-iy|
                unsigned int byte = b1 * 48u + b2 + Cc;    // patch byte offset
                t16[j] = (unsigned int)*(const unsigned short*)(
                    patc + (unsigned int)(j * PAT_SENS_B) + byte);  // swz((t-tmin)<<4)
            }
#pragma unroll
            for (int j = 0; j < CHUNK; ++j) {
                uint4 w = *(const uint4*)(winc + (unsigned int)(j << 10) + t16[j]);
                f32x2 p0 = {bflo(w.x), bfhi(w.x)};  // ch0,1
                f32x2 p1 = {bflo(w.y), bfhi(w.y)};  // ch2,3
                f32x2 p2 = {bflo(w.z), bfhi(w.z)};  // ch4,5
                f32x2 p3 = {bflo(w.w), bfhi(w.w)};  // ch6,7
                acc2[0] += p0;  // v_pk_add_f32; per-channel s-ascending order kept
                acc2[1] += p1;
                acc2[2] += p2;
                acc2[3] += p3;
            }
        }

        if (c + 1 < NCHUNK) WRITEBUF(c + 1);
        __syncthreads();
    }
#undef ISSUE
#undef WRITEBUF

    int pix = (ix << 9) | iy;
#pragma unroll
    for (int k = 0; k < 4; ++k) {
        out[(2 * k) * NPIX + pix] = acc2[k].x;
        out[(2 * k + 1) * NPIX + pix] = acc2[k].y;
    }
}

// ---------- fallback path (ws too small): r5-proven build_table + das_main ----------
__global__ __launch_bounds__(256) void build_table(unsigned short* __restrict__ tab) {
    int idx = blockIdx.x * 256 + threadIdx.x;
    tab[idx] = delay_entry(idx >> 9, idx & 511);  // RAW (unscaled) for das_main
}

__global__ __launch_bounds__(256) void das_main(const float* __restrict__ data,
                                                const unsigned short* __restrict__ tab,
                                                const int* __restrict__ sxy,
                                                float* __restrict__ out) {
    __shared__ int sx[S_CNT];
    __shared__ int sy[S_CNT];
    int tid = threadIdx.x;
    if (tid < S_CNT) {
        sx[tid] = sxy[2 * tid];
        sy[tid] = sxy[2 * tid + 1];
    }
    __syncthreads();
    int iy = ((blockIdx.x & 31) << 4) | (tid & 15);
    int ix = ((blockIdx.x >> 5) << 4) | (tid >> 4);
    float acc[CH];
#pragma unroll
    for (int k = 0; k < CH; ++k) acc[k] = 0.0f;
#pragma unroll 4
    for (int s = 0; s < S_CNT; ++s) {
        int dxi = sx[s] - ix;
        int dyi = sy[s] - iy;
        int adx = dxi < 0 ? -dxi : dxi;
        int ady = dyi < 0 ? -dyi : dyi;
        int t = (int)tab[(adx << 9) | ady];
        const float* p = data + (s << 11) + t;
#pragma unroll
        for (int k = 0; k < CH; ++k) acc[k] += p[(size_t)k * CH_STRIDE];
    }
    int pix = (ix << 9) | iy;
#pragma unroll
    for (int k = 0; k < CH; ++k) out[k * NPIX + pix] = acc[k];
}

extern "C" void kernel_launch(void* const* d_in, const int* in_sizes, int n_in,
                              void* d_out, int out_size, void* d_ws, size_t ws_size,
                              hipStream_t stream) {
    const float* data = (const float*)d_in[0];     // (4,2,128,2048) f32
    const int* sxy = (const int*)d_in[1];          // (128,2) i32
    float* out = (float*)d_out;                    // (4,2,512,512) f32
    unsigned short* tab = (unsigned short*)d_ws;   // 512 KB (prescaled)

    size_t need = (size_t)TAB_BYTES + (size_t)D2B_BYTES + (size_t)META_BYTES;
    if (ws_size >= need) {
        uint4* d2b = (uint4*)((char*)d_ws + TAB_BYTES);
        uint4* meta = (uint4*)((char*)d_ws + TAB_BYTES + D2B_BYTES);
        prep<<<NPIX / 256, 256, 0, stream>>>(data, sxy, tab, d2b, meta);
        das_smeta<<<NTILE, 256, 0, stream>>>(d2b, meta, out);
    } else {
        build_table<<<NPIX / 256, 256, 0, stream>>>(tab);
        das_main<<<1024, 256, 0, stream>>>(data, tab, sxy, out);
    }
}

// Round 10
// 99.585 us; speedup vs baseline: 1.1202x; 1.0117x over previous
//
#include <hip/hip_runtime.h>
#include <math.h>

// DAS beamforming: out[b][c][p] = sum_s data[b][c][s][t(s,p)]
// Table chain: ONLY the f64-emulated chain is proven bit-exact (r5/r6/r8
// absmax 0.0). r7's native-f32 version regressed (3.56). DO NOT change it.
// r10: divergent VMEM gather ~40us. r11-r16: every restructure lands 40-54us.
// r17/r19: SGPR meta + dbuf + 1 barrier/pass: 45.7us == r16's 45.5. ZERO
//   delta from deleting broadcasts+barriers; conflicts identical (1631263).
//   CONCLUSION: LDS (~19us) + VALU (~22us) do NOT overlap -- 16 waves/CU in
//   4 barrier-aligned blocks convoy through identical micro-phases
//   (VALUBusy 50%, Occupancy 28%). Parallelism, not instruction count, is
//   the remaining lever.
// r20 (this round): sensor-split. Each 16x16 tile computed by TWO blocks
//   (sensors 0-63 / 64-127), CHUNK=4 -> 15KB LDS -> 8 blocks/CU = 32
//   waves/CU full occupancy, 8 independent stagger-phased barrier groups.
//   Halves write partial images; float4 combine kernel adds them (~5us).
//   Per-half accumulation order preserved; (p0)+(p1) reorder delta ~1e-5
//   vs 1.08 tolerance. Everything else r17-proven.

#define NXY 512
#define S_CNT 128
#define T_CNT 2048
#define CH 8                       // B*2 = 4*2
#define CH_STRIDE (S_CNT * T_CNT)  // 262144 floats between channels (orig layout)
#define NPIX (NXY * NXY)
#define NTILE 1024                 // 32x32 tiles of 16x16 px
#define TAB_BYTES (NPIX * 2)       // 512 KB u16 table (prescaled t<<4)
#define D2B_BYTES (CH_STRIDE * 16) // 4 MB
#define META_BYTES (NTILE * S_CNT * 16)  // 2 MB
#define PART_BYTES (2 * CH * NPIX * 4)   // 16.8 MB (two f32 partial images)
#define HCNT 64                    // sensors per half-block
#define CHUNK 4                    // sensors per LDS pass
#define NPASS (HCNT / CHUNK)       // 16 passes
#define WIN 64                     // window entries per sensor (span <= 56 proven)
#define PATW 24                    // patch width u16 (16B-aligned rows)
#define PAT_SENS_B (16 * PATW * 2) // 768 B/sensor

typedef float f32x2 __attribute__((ext_vector_type(2)));

#if __has_builtin(__builtin_amdgcn_sad_u32)
__device__ __forceinline__ unsigned int sadu(unsigned int a, unsigned int b, unsigned int c) {
    return __builtin_amdgcn_sad_u32(a, b, c);
}
#else
__device__ __forceinline__ unsigned int sadu(unsigned int a, unsigned int b, unsigned int c) {
    return (a > b ? a - b : b - a) + c;  // compiler selects v_sad_u32
}
#endif

__device__ __forceinline__ unsigned short delay_entry(int adx, int ady) {
    const double DX32 = (double)1e-4f;                        // f32 const, exact widen
    const double R1 = (double)(float)(1.0 / 1550.0);          // CR f32 reciprocal
    const double R2 = (double)(float)(1.0 / (double)2.5e-8f); // = 4.0e7 exactly
    float dxf = (float)((double)adx * DX32);        // exact f64 product -> f32 round
    float dyf = (float)((double)ady * DX32);
    float a2 = (float)((double)dxf * (double)dxf);  // exact in f64 -> f32 round
    float b2 = (float)((double)dyf * (double)dyf);  // exact in f64 -> f32 round
    float sum = (float)((double)a2 + (double)b2);   // exact in f64 -> f32 round
    float dis = (float)sqrt((double)sum);           // CR f32 sqrt
    float q1 = (float)((double)dis * R1);           // CR f32 mul
    float q2 = (float)((double)q1 * R2);            // CR f32 mul
    return (unsigned short)(int)q2;                 // trunc; max 1864
}

__device__ __forceinline__ unsigned int bf16_rne(float f) {
    unsigned int x = __float_as_uint(f);
    return (x + 0x7fffu + ((x >> 16) & 1u)) >> 16;  // round-to-nearest-even
}

// Fused: prescaled table + bf16 transpose-pack + per-(tile,sensor) META.
__global__ __launch_bounds__(256) void prep(const float* __restrict__ data,
                                            const int* __restrict__ sxy,
                                            unsigned short* __restrict__ tab,
                                            uint4* __restrict__ d2b,
                                            uint4* __restrict__ meta) {
    int idx = blockIdx.x * 256 + threadIdx.x;  // 0 .. 262143 (NPIX == 128*2048)
    tab[idx] = (unsigned short)((unsigned int)delay_entry(idx >> 9, idx & 511) << 4);

    unsigned int w[4];
#pragma unroll
    for (int j = 0; j < 4; ++j) {
        unsigned int lo = bf16_rne(data[(2 * j) * CH_STRIDE + idx]);
        unsigned int hi = bf16_rne(data[(2 * j + 1) * CH_STRIDE + idx]);
        w[j] = lo | (hi << 16);
    }
    d2b[idx] = make_uint4(w[0], w[1], w[2], w[3]);

    if (idx < NTILE * S_CNT) {
        int tile = idx >> 7;
        int s = idx & 127;
        int x0 = (tile >> 5) << 4;
        int y0 = (tile & 31) << 4;
        int sxv = sxy[2 * s];
        int syv = sxy[2 * s + 1];
        int axm = sxv < x0 ? x0 - sxv : (sxv > x0 + 15 ? sxv - x0 - 15 : 0);
        int aym = syv < y0 ? y0 - syv : (syv > y0 + 15 ? syv - y0 - 15 : 0);
        int ay0 = aym & ~7;                          // 16B-align patch rows
        int tmin = (int)delay_entry(axm, aym);       // exact monotone lower bound
        meta[idx] = make_uint4((unsigned int)sxv, (unsigned int)(2 * syv),
                               (unsigned int)(axm | (ay0 << 16)),
                               (unsigned int)(tmin << 4));
    }
}

__device__ __forceinline__ float bflo(unsigned int u) { return __uint_as_float(u << 16); }
__device__ __forceinline__ float bfhi(unsigned int u) { return __uint_as_float(u & 0xffff0000u); }

// window bank swizzle: entry byte offset d (=e<<4): XOR bits[5:4] with d[8:7]
__device__ __forceinline__ unsigned int swz16(unsigned int d) {
    return d ^ (((d >> 7) & 3u) << 4);
}
// per-halfword: swz((a - tm4) mod 2^16); used entries land in [0, 56<<4]
__device__ __forceinline__ unsigned int subswz_x2(unsigned int a, unsigned int tm4) {
    unsigned int lo = swz16((a - tm4) & 0xffffu);
    unsigned int hi = swz16(((a >> 16) - tm4) & 0xffffu);
    return lo | (hi << 16);
}

// Gather v8: half-sensor blocks. grid 2048 = (tile, half). 15 KB LDS ->
// 8 blocks/CU = 32 waves/CU. Double-buffered, 1 barrier/pass (r17 shape).
__global__ __launch_bounds__(256) void das_ghalf(const uint4* __restrict__ d2b,
                                                 const uint4* __restrict__ meta,
                                                 float* __restrict__ part) {
    __shared__ uint2 mstage[HCNT];             // ax0|ay0<<16, tmin<<4 (512 B)
    __shared__ uint4 winb[2][CHUNK * WIN];     // swizzled windows, 2 x 4 KB
    __shared__ uint4 patb[2][CHUNK * 16 * 3];  // pre-sub/pre-swz patches, 2 x 3 KB

    int tid = threadIdx.x;
    int tile = blockIdx.x >> 1;
    int h = blockIdx.x & 1;
    // meta for this block's 64 sensors (uniform base -> SGPR path)
    const uint4* mblk = meta + ((size_t)tile << 7) + ((size_t)h << 6);
    // d2b base for this half's sensors
    const uint4* d2bh = d2b + ((size_t)(h * HCNT) << 11);

    if (tid < HCNT) {
        uint4 m = mblk[tid];
        mstage[tid] = make_uint2(m.z, m.w);
    }
    __syncthreads();

    // lane bits: iy[2:0]=tid[2:0], ix[2:0]=tid[5:3]; wave bits: iy[3]=tid[6], ix[3]=tid[7]
    int y0 = (tile & 31) << 4;
    int x0 = (tile >> 5) << 4;
    int iy = y0 | (((tid >> 6) & 1) << 3) | (tid & 7);
    int ix = x0 | ((tid >> 7) << 3) | ((tid >> 3) & 7);
    unsigned int uix = (unsigned int)ix;
    unsigned int uiy2 = (unsigned int)(2 * iy);

    f32x2 acc2[4];
#pragma unroll
    for (int k = 0; k < 4; ++k) acc2[k] = (f32x2){0.0f, 0.0f};

    // prefetch registers (pass c+1 in flight during INNER(c))
    uint4 rw0, rp0;
    unsigned int wslot, pslot0, ptm0;
    const int lsw = tid >> 6, e0 = tid & 63;   // window: 1 uint4/thread/pass
    const unsigned int swn = (((unsigned int)e0 >> 3) & 3u) << 4;
    const bool pact = tid < 192;  // patches: 4 sensors x 48 uint4 = 192 loads

    // tab lives immediately before d2b in ws: recover its base from d2b.
    const char* tab_g = (const char*)d2b - TAB_BYTES;

#define ISSUE(cc)                                                                     \
    {                                                                                 \
        int s0n = (cc) * CHUNK;                                                       \
        uint2 stw = mstage[s0n + lsw];                                                \
        rw0 = d2bh[((size_t)(s0n + lsw) << 11) + (stw.y >> 4) + e0];                  \
        wslot = ((unsigned int)lsw << 10) | (((unsigned int)e0 << 4) ^ swn);          \
        if (pact) {                                                                   \
            unsigned int pidx = (unsigned int)tid;                                    \
            unsigned int r3 = pidx / 3u, cc2 = pidx - r3 * 3u;                        \
            unsigned int row = r3 & 15u, ls = r3 >> 4;                                \
            uint2 stp = mstage[s0n + ls];                                             \
            rp0 = *(const uint4*)(tab_g +                                             \
                ((((stp.x & 0xffffu) + row) << 10) + ((stp.x >> 16) << 1) + (cc2 << 4))); \
            pslot0 = ls * 768u + row * 48u + cc2 * 16u;                               \
            ptm0 = stp.y;                                                             \
        }                                                                             \
    }

#define WRITEBUF(cc)                                                                  \
    {                                                                                 \
        char* wb = (char*)winb[(cc) & 1];                                             \
        char* pb = (char*)patb[(cc) & 1];                                             \
        *(uint4*)(wb + wslot) = rw0;                                                  \
        if (pact) {                                                                   \
            uint4 v = rp0;                                                            \
            v.x = subswz_x2(v.x, ptm0);                                               \
            v.y = subswz_x2(v.y, ptm0);                                               \
            v.z = subswz_x2(v.z, ptm0);                                               \
            v.w = subswz_x2(v.w, ptm0);                                               \
            *(uint4*)(pb + pslot0) = v;                                               \
        }                                                                             \
    }

    ISSUE(0);
    WRITEBUF(0);
    __syncthreads();

    for (int c = 0; c < NPASS; ++c) {
        if (c + 1 < NPASS) ISSUE(c + 1);

        {  // INNER(c): SGPR meta, 2 LDS reads/pair, phase-split for ILP
            const char* patc = (const char*)patb[c & 1];
            const char* winc = (const char*)winb[c & 1];
            int s0 = c * CHUNK;
            unsigned int t16[CHUNK];
#pragma unroll
            for (int j = 0; j < CHUNK; ++j) {
                uint4 m = mblk[s0 + j];  // uniform -> s_load_dwordx4
                unsigned int Cc = 0u - ((m.z & 0xffffu) * 48u + (m.z >> 16) * 2u);  // SALU
                unsigned int b1 = sadu(m.x, uix, 0u);      // |sx-ix|
                unsigned int b2 = sadu(m.y, uiy2, 0u);     // 2|sy-iy|
                unsigned int byte = b1 * 48u + b2 + Cc;    // patch byte offset
                t16[j] = (unsigned int)*(const unsigned short*)(
                    patc + (unsigned int)(j * PAT_SENS_B) + byte);  // swz((t-tmin)<<4)
            }
#pragma unroll
            for (int j = 0; j < CHUNK; ++j) {
                uint4 w = *(const uint4*)(winc + (unsigned int)(j << 10) + t16[j]);
                f32x2 p0 = {bflo(w.x), bfhi(w.x)};  // ch0,1
                f32x2 p1 = {bflo(w.y), bfhi(w.y)};  // ch2,3
                f32x2 p2 = {bflo(w.z), bfhi(w.z)};  // ch4,5
                f32x2 p3 = {bflo(w.w), bfhi(w.w)};  // ch6,7
                acc2[0] += p0;  // v_pk_add_f32; per-channel s-ascending order kept
                acc2[1] += p1;
                acc2[2] += p2;
                acc2[3] += p3;
            }
        }

        if (c + 1 < NPASS) WRITEBUF(c + 1);
        __syncthreads();
    }
#undef ISSUE
#undef WRITEBUF

    float* outp = part + (size_t)h * (CH * NPIX);
    int pix = (ix << 9) | iy;
#pragma unroll
    for (int k = 0; k < 4; ++k) {
        outp[(2 * k) * NPIX + pix] = acc2[k].x;
        outp[(2 * k + 1) * NPIX + pix] = acc2[k].y;
    }
}

// out = p0 + p1 (float4-vectorized; 2048 blocks x 256 threads)
__global__ __launch_bounds__(256) void combine(const float4* __restrict__ p0,
                                               const float4* __restrict__ p1,
                                               float4* __restrict__ out) {
    int i = blockIdx.x * 256 + threadIdx.x;
    float4 a = p0[i];
    float4 b = p1[i];
    out[i] = make_float4(a.x + b.x, a.y + b.y, a.z + b.z, a.w + b.w);
}

// ---------- fallback path (ws too small): r5-proven build_table + das_main ----------
__global__ __launch_bounds__(256) void build_table(unsigned short* __restrict__ tab) {
    int idx = blockIdx.x * 256 + threadIdx.x;
    tab[idx] = delay_entry(idx >> 9, idx & 511);  // RAW (unscaled) for das_main
}

__global__ __launch_bounds__(256) void das_main(const float* __restrict__ data,
                                                const unsigned short* __restrict__ tab,
                                                const int* __restrict__ sxy,
                                                float* __restrict__ out) {
    __shared__ int sx[S_CNT];
    __shared__ int sy[S_CNT];
    int tid = threadIdx.x;
    if (tid < S_CNT) {
        sx[tid] = sxy[2 * tid];
        sy[tid] = sxy[2 * tid + 1];
    }
    __syncthreads();
    int iy = ((blockIdx.x & 31) << 4) | (tid & 15);
    int ix = ((blockIdx.x >> 5) << 4) | (tid >> 4);
    float acc[CH];
#pragma unroll
    for (int k = 0; k < CH; ++k) acc[k] = 0.0f;
#pragma unroll 4
    for (int s = 0; s < S_CNT; ++s) {
        int dxi = sx[s] - ix;
        int dyi = sy[s] - iy;
        int adx = dxi < 0 ? -dxi : dxi;
        int ady = dyi < 0 ? -dyi : dyi;
        int t = (int)tab[(adx << 9) | ady];
        const float* p = data + (s << 11) + t;
#pragma unroll
        for (int k = 0; k < CH; ++k) acc[k] += p[(size_t)k * CH_STRIDE];
    }
    int pix = (ix << 9) | iy;
#pragma unroll
    for (int k = 0; k < CH; ++k) out[k * NPIX + pix] = acc[k];
}

extern "C" void kernel_launch(void* const* d_in, const int* in_sizes, int n_in,
                              void* d_out, int out_size, void* d_ws, size_t ws_size,
                              hipStream_t stream) {
    const float* data = (const float*)d_in[0];     // (4,2,128,2048) f32
    const int* sxy = (const int*)d_in[1];          // (128,2) i32
    float* out = (float*)d_out;                    // (4,2,512,512) f32
    unsigned short* tab = (unsigned short*)d_ws;   // 512 KB (prescaled)

    size_t need = (size_t)TAB_BYTES + (size_t)D2B_BYTES + (size_t)META_BYTES +
                  (size_t)PART_BYTES;
    if (ws_size >= need) {
        uint4* d2b = (uint4*)((char*)d_ws + TAB_BYTES);
        uint4* meta = (uint4*)((char*)d_ws + TAB_BYTES + D2B_BYTES);
        float* part = (float*)((char*)d_ws + TAB_BYTES + D2B_BYTES + META_BYTES);
        prep<<<NPIX / 256, 256, 0, stream>>>(data, sxy, tab, d2b, meta);
        das_ghalf<<<2 * NTILE, 256, 0, stream>>>(d2b, meta, part);
        combine<<<CH * NPIX / 1024, 256, 0, stream>>>(
            (const float4*)part, (const float4*)(part + CH * NPIX), (float4*)out);
    } else {
        build_table<<<NPIX / 256, 256, 0, stream>>>(tab);
        das_main<<<1024, 256, 0, stream>>>(data, tab, sxy, out);
    }
}